// Round 7
// baseline (332.150 us; speedup 1.0000x reference)
//
#include <hip/hip_runtime.h>

#define RR 4
#define NS 17
#define BB 4
#define CC 128
#define HH 96
#define WW 160
#define HWSZ (HH * WW)

// 512-thread block = two 256-thread channel-halves sharing one 32x8 pixel
// tile. Each half runs the round-1-proven inner loop (store-early, 2
// barriers/group, prefetch after first barrier) on its own 16 channels in
// its own LDS buffer; halves combine via LDS, then half A does a single
// 4-writer atomic pass.
//
// WHY: occupancy. 1 px/thread + CCHUNK=32 caps 256-thread blocks at 3840
// waves (15/CU, 47%). Splitting channels across MORE BLOCKS (rounds 2/5/6)
// makes 8-writer outputs, which cost 34-40 B/atomic instead of 4 B
// regardless of XCD placement (counter-proven r0 vs r5/r6). Fusing the
// split INSIDE the block doubles waves (7680, 30/CU) with writers still 4.
//
// TRIPWIRE: WRITE_SIZE must be ~16,320 KB (4 B/atomic). If inflated,
// abandon atomics (workspace partials + reduce kernel).
// DO NOT write-late/double-buffer the LDS loop (rounds 2-3 regression).
#define TW 32
#define HTILE 8
#define TROWS (HTILE + 2 * RR)   // 16
#define TCOLS (TW + 2 * RR)      // 40
#define TILE_E (TROWS * TCOLS)   // 640 float4 = 10240 B per half-buffer
#define CCHUNK 32                // channels per BLOCK -> 4 writers/output
#define NCHUNK (CC / CCHUNK)     // 4 (atomic-accumulated)
#define CHALF (CCHUNK / 2)       // 16 channels per half
#define CG 4                     // channels per group (float4)
#define NGH (CHALF / CG)         // 4 groups per half
#define NSPX (WW / TW)           // 5
#define NSPY (HH / HTILE)        // 12

#define FMA4(a, t) \
    (a) = fmaf(svx, (t).x, fmaf(svy, (t).y, fmaf(svz, (t).z, fmaf(svw, (t).w, (a)))))

__global__ __launch_bounds__(512, 8)
void cost_volume_kernel(const float* __restrict__ src,
                        const float* __restrict__ tgt,
                        float* __restrict__ out) {
    __shared__ float4 tile[2][TILE_E];    // one buffer per half: 20480 B

    const int x    = threadIdx.x;         // 0..31
    const int yy   = threadIdx.y;         // 0..15
    const int half = yy >> 3;             // 0/1 channel half (wave-uniform)
    const int hg   = yy & 7;              // 0..7 pixel row group
    const int tid  = hg * TW + x;         // 0..255 within half

    const int wx = blockIdx.x;            // 0..4   (w tile)
    const int wy = blockIdx.y;            // 0..11  (h tile)
    const int z  = blockIdx.z;            // 0..15  (z = ch*4 + b)
    const int b  = z & 3;
    const int c0 = (z >> 2) * CCHUNK + half * CHALF;

    const int w0 = wx * TW;
    const int h0 = wy * HTILE;

    const int w = w0 + x;                 // always < WW
    const int h = h0 + hg;                // always < HH

    const float* tgt_b = tgt + (size_t)(b * CC + c0) * HWSZ;
    const float* src_p = src + (size_t)(b * CC + c0) * HWSZ + h * WW + w;

    // --- precompute staging slots (invariant across channel groups) ---
    int  sOff[3];
    bool sVal[3];
#pragma unroll
    for (int k = 0; k < 3; ++k) {
        const int idx = tid + k * 256;
        const int r   = idx / TCOLS;
        const int col = idx - r * TCOLS;
        const int gr  = h0 - RR + r;
        const int gc  = w0 - RR + col;
        sVal[k] = (idx < TILE_E) && gr >= 0 && gr < HH && gc >= 0 && gc < WW;
        sOff[k] = gr * WW + gc;
    }

    float4 pre[3];                        // tgt tile prefetch (3 f4/thread)
    float  sv4[4];                        // src prefetch (4 channels)

    auto fetch = [&](int g) {
        const float* t = tgt_b + (size_t)(g * CG) * HWSZ;
#pragma unroll
        for (int k = 0; k < 3; ++k) {
            float4 v = make_float4(0.f, 0.f, 0.f, 0.f);
            if (sVal[k]) {
                const float* p = t + sOff[k];
                v.x = p[0];
                v.y = p[HWSZ];
                v.z = p[2 * HWSZ];
                v.w = p[3 * HWSZ];
            }
            pre[k] = v;
        }
        const float* s = src_p + (size_t)(g * CG) * HWSZ;
#pragma unroll
        for (int k = 0; k < 4; ++k) sv4[k] = s[k * HWSZ];
    };

    float acc[NS];
#pragma unroll
    for (int s = 0; s < NS; ++s) acc[s] = 0.f;

    fetch(0);
    const int base = (RR + hg) * TCOLS + (RR + x);
    float4* tb = tile[half];

    for (int g = 0; g < NGH; ++g) {
        // write staged regs to this half's LDS buffer (store-early, proven)
        tb[tid]       = pre[0];
        tb[tid + 256] = pre[1];
        if (tid + 512 < TILE_E) tb[tid + 512] = pre[2];
        const float svx = sv4[0], svy = sv4[1], svz = sv4[2], svw = sv4[3];
        __syncthreads();

        // prefetch next group while computing this one
        if (g + 1 < NGH) fetch(g + 1);

        // compute: 17 ds_read_b128 + 68 FMAs (4 channels at once)
        {
            float4 tc = tb[base];
            FMA4(acc[0], tc);
#pragma unroll
            for (int off = 1; off <= RR; ++off) {
                float4 tu = tb[base - off * TCOLS];
                float4 td = tb[base + off * TCOLS];
                float4 tl = tb[base - off];
                float4 tr = tb[base + off];
                FMA4(acc[4 * off - 3], tu);
                FMA4(acc[4 * off - 2], td);
                FMA4(acc[4 * off - 1], tl);
                FMA4(acc[4 * off    ], tr);
            }
        }
        __syncthreads();
    }

    // --- combine halves in LDS, then 4-writer atomic epilogue ---
    // (last loop barrier ordered all tile reads before this reuse)
    // stride NS=17 is odd -> conflict-free across 32 banks; 4352 floats
    // fit in the 5120-float tile allocation.
    float* red = (float*)tile;
    if (half) {
#pragma unroll
        for (int s = 0; s < NS; ++s) red[tid * NS + s] = acc[s];
    }
    __syncthreads();
    if (!half) {
        float* op = out + (((size_t)b * NS) * HH + h) * WW + w;
#pragma unroll
        for (int s = 0; s < NS; ++s) {
            atomicAdd(op + (size_t)s * HWSZ, acc[s] + red[tid * NS + s]);
        }
    }
}

extern "C" void kernel_launch(void* const* d_in, const int* in_sizes, int n_in,
                              void* d_out, int out_size, void* d_ws, size_t ws_size,
                              hipStream_t stream) {
    const float* src = (const float*)d_in[0];
    const float* tgt = (const float*)d_in[1];
    float* out = (float*)d_out;

    // d_out is poisoned before every launch; we accumulate atomically -> zero it
    hipMemsetAsync(out, 0, (size_t)out_size * sizeof(float), stream);

    dim3 block(TW, 16, 1);                   // 512 threads = two 256-halves
    dim3 grid(NSPX, NSPY, BB * NCHUNK);      // (5, 12, 16) = 960 blocks
    cost_volume_kernel<<<grid, block, 0, stream>>>(src, tgt, out);
}

// Round 8
// 130.847 us; speedup vs baseline: 2.5385x; 2.5385x over previous
//
#include <hip/hip_runtime.h>

#define RR 4
#define NS 17
#define BB 4
#define CC 128
#define HH 96
#define WW 160
#define HWSZ (HH * WW)

// Round-1 proven kernel (38us kernel / 106us bench, reproduced twice) with
// ONE delta: prefetch depth 1 -> 2 (prA/prB ping-pong, manual unroll-by-2).
// Everything else bit-identical: 960 blocks, 256 threads, (256,4) bounds,
// store-early + 2 barriers/group, XCD swizzle, 4-writer atomic epilogue.
//
// SESSION LAWS (counter-proven):
//  - VGPR envelope: live set ~50-70 regs. NEVER tighten launch_bounds
//    (r7: (512,8) forced VGPR=32 -> acc[] in scratch -> 400+ MB sym
//    fetch/write inflation; r2: (256,6)/VGPR=40 same mechanism).
//  - Writers/output must stay 4 (r5/r6: 8 writers -> 34 B/atomic vs 4 B,
//    independent of XCD placement).
//  - Store-early loop only (write-late r2/r3 regressed; partly spill).
// TRIPWIRES this round: WRITE_SIZE == 16,320 KB; VGPR < 128; FETCH ~75 MB.
#define TW 32
#define HTILE 8
#define TROWS (HTILE + 2 * RR)   // 16
#define TCOLS (TW + 2 * RR)      // 40
#define TILE_E (TROWS * TCOLS)   // 640 float4 elements = 10240 B
#define CCHUNK 32                // channels per block
#define NCHUNK (CC / CCHUNK)     // 4 (atomic-accumulated, 4 writers/output)
#define CG 4                     // channels per group (float4)
#define NG (CCHUNK / CG)         // 8 groups per block
#define NSPX (WW / TW)           // 5
#define NSPY (HH / HTILE)        // 12
#define NSP (NSPX * NSPY)        // 60 spatial tiles
#define NWG (NSP * BB * NCHUNK)  // 960 workgroups
#define NXCD 8
#define WGPX (NWG / NXCD)        // 120 (exact)

#define FMA4(a, t) \
    (a) = fmaf(svx, (t).x, fmaf(svy, (t).y, fmaf(svz, (t).z, fmaf(svw, (t).w, (a)))))

__global__ __launch_bounds__(256, 4)
void cost_volume_kernel(const float* __restrict__ src,
                        const float* __restrict__ tgt,
                        float* __restrict__ out) {
    __shared__ float4 tile[TILE_E];

    const int x   = threadIdx.x;          // 0..31
    const int hg  = threadIdx.y;          // 0..7
    const int tid = hg * TW + x;          // 0..255

    // XCD-aware bijective swizzle (r1-proven): each XCD gets a contiguous
    // wg range, spatial-fastest -> halo re-reads hit that XCD's L2.
    const int flat = blockIdx.x;                      // dispatch id, 0..959
    const int wg   = (flat & (NXCD - 1)) * WGPX + (flat >> 3);
    const int sp   = wg % NSP;                        // spatial tile (x-fastest)
    const int z    = wg / NSP;                        // 0..15
    const int wx   = sp % NSPX;
    const int wy   = sp / NSPX;

    const int w0 = wx * TW;
    const int h0 = wy * HTILE;
    const int b  = z & 3;
    const int c0 = (z >> 2) * CCHUNK;

    const int w = w0 + x;                 // always < WW
    const int h = h0 + hg;                // always < HH

    const float* tgt_b = tgt + (size_t)(b * CC + c0) * HWSZ;
    const float* src_p = src + (size_t)(b * CC + c0) * HWSZ + h * WW + w;

    // --- precompute staging slots (invariant across channel groups) ---
    int  sOff[3];
    bool sVal[3];
#pragma unroll
    for (int k = 0; k < 3; ++k) {
        const int idx = tid + k * 256;
        const int r   = idx / TCOLS;
        const int col = idx - r * TCOLS;
        const int gr  = h0 - RR + r;
        const int gc  = w0 - RR + col;
        sVal[k] = (idx < TILE_E) && gr >= 0 && gr < HH && gc >= 0 && gc < WW;
        sOff[k] = gr * WW + gc;
    }

    // depth-2 prefetch state: two named register sets (static indexing only)
    float4 prA[3], prB[3];
    float  svA[4], svB[4];

    auto fetch = [&](int g, float4 pr[3], float sv[4]) {
        const float* t = tgt_b + (size_t)(g * CG) * HWSZ;
#pragma unroll
        for (int k = 0; k < 3; ++k) {
            float4 v = make_float4(0.f, 0.f, 0.f, 0.f);
            if (sVal[k]) {
                const float* p = t + sOff[k];
                v.x = p[0];
                v.y = p[HWSZ];
                v.z = p[2 * HWSZ];
                v.w = p[3 * HWSZ];
            }
            pr[k] = v;
        }
        const float* s = src_p + (size_t)(g * CG) * HWSZ;
#pragma unroll
        for (int k = 0; k < 4; ++k) sv[k] = s[k * HWSZ];
    };

    float acc[NS];
#pragma unroll
    for (int s = 0; s < NS; ++s) acc[s] = 0.f;

    // prologue: two groups in flight
    fetch(0, prA, svA);
    fetch(1, prB, svB);

    const int base = (RR + hg) * TCOLS + (RR + x);

    auto compute = [&](float svx, float svy, float svz, float svw) {
        float4 tc = tile[base];
        FMA4(acc[0], tc);
#pragma unroll
        for (int off = 1; off <= RR; ++off) {
            float4 tu = tile[base - off * TCOLS];
            float4 td = tile[base + off * TCOLS];
            float4 tl = tile[base - off];
            float4 tr = tile[base + off];
            FMA4(acc[4 * off - 3], tu);
            FMA4(acc[4 * off - 2], td);
            FMA4(acc[4 * off - 1], tl);
            FMA4(acc[4 * off    ], tr);
        }
    };

    // PHASE: store staged group (store-early), snapshot src scalars, barrier,
    // REFILL the just-freed register set with group g+2 (2-group flight
    // window ~800cyc >= HBM latency), compute, barrier.
#define PHASE(PR, SV, GNEXT)                                        \
    do {                                                            \
        tile[tid]       = PR[0];                                    \
        tile[tid + 256] = PR[1];                                    \
        if (tid + 512 < TILE_E) tile[tid + 512] = PR[2];            \
        const float svx = SV[0], svy = SV[1],                       \
                    svz = SV[2], svw = SV[3];                       \
        __syncthreads();                                            \
        if ((GNEXT) < NG) fetch((GNEXT), PR, SV);                   \
        compute(svx, svy, svz, svw);                                \
        __syncthreads();                                            \
    } while (0)

    for (int k = 0; k < NG / 2; ++k) {
        PHASE(prA, svA, 2 * k + 2);
        PHASE(prB, svB, 2 * k + 3);
    }
#undef PHASE

    // epilogue: atomic accumulate (4 channel-chunk writers per output)
    float* op = out + (((size_t)b * NS) * HH + h) * WW + w;
#pragma unroll
    for (int s = 0; s < NS; ++s) {
        atomicAdd(op + (size_t)s * HWSZ, acc[s]);
    }
}

extern "C" void kernel_launch(void* const* d_in, const int* in_sizes, int n_in,
                              void* d_out, int out_size, void* d_ws, size_t ws_size,
                              hipStream_t stream) {
    const float* src = (const float*)d_in[0];
    const float* tgt = (const float*)d_in[1];
    float* out = (float*)d_out;

    // d_out is poisoned before every launch; we accumulate atomically -> zero it
    hipMemsetAsync(out, 0, (size_t)out_size * sizeof(float), stream);

    dim3 block(TW, 8, 1);      // 256 threads
    dim3 grid(NWG, 1, 1);      // 960 blocks
    cost_volume_kernel<<<grid, block, 0, stream>>>(src, tgt, out);
}

// Round 9
// 106.254 us; speedup vs baseline: 3.1260x; 1.2314x over previous
//
#include <hip/hip_runtime.h>

#define RR 4
#define NS 17
#define BB 4
#define CC 128
#define HH 96
#define WW 160
#define HWSZ (HH * WW)

// Round-1 proven skeleton (38us kernel / 106us bench, reproduced twice) with
// ONE delta: phase width CG 4 -> 8 (two float4 LDS buffers, NG 8 -> 4).
// Skeleton preserved literally: store-early, barrier, fetch(g+1), compute,
// barrier; depth-1 prefetch; 960 blocks; r1 swizzle; 4-writer atomics.
//
// SESSION LAWS (counter-proven):
//  - ONLY the r1 phase skeleton has clean 4 B/atomic writes. Deviations
//    measured dirty: write-late (r2/r3), 8 writers/output (r5/r6, 34 B/at
//    placement-independent), depth-2 A/B pipeline (r8, 15 B/at).
//  - VGPR envelope: never tighten launch_bounds below the ~100-reg live set
//    (r7: forced VGPR=32 -> acc in scratch -> 400+MB symmetric traffic).
//  - Occupancy levers via more blocks or bigger blocks both failed; the
//    remaining lever is stall reduction per phase (this round: fewer
//    barriers, wider compute to cover HBM latency).
// TRIPWIRES: WRITE_SIZE == ~16,320 KB; VGPR <= 128 with no symmetric
// fetch/write inflation; FETCH ~72-85 MB.
#define TW 32
#define HTILE 8
#define TROWS (HTILE + 2 * RR)   // 16
#define TCOLS (TW + 2 * RR)      // 40
#define TILE_E (TROWS * TCOLS)   // 640 float4 elements = 10240 B per buffer
#define CCHUNK 32                // channels per block
#define NCHUNK (CC / CCHUNK)     // 4 (atomic-accumulated, 4 writers/output)
#define CG 8                     // channels per phase (2x float4)
#define NG (CCHUNK / CG)         // 4 phases per block
#define NSPX (WW / TW)           // 5
#define NSPY (HH / HTILE)        // 12
#define NSP (NSPX * NSPY)        // 60 spatial tiles
#define NWG (NSP * BB * NCHUNK)  // 960 workgroups
#define NXCD 8
#define WGPX (NWG / NXCD)        // 120 (exact)

#define FMA4S(a, t, s0, s1, s2, s3) \
    (a) = fmaf((s0), (t).x, fmaf((s1), (t).y, fmaf((s2), (t).z, fmaf((s3), (t).w, (a)))))

__global__ __launch_bounds__(256, 4)
void cost_volume_kernel(const float* __restrict__ src,
                        const float* __restrict__ tgt,
                        float* __restrict__ out) {
    __shared__ float4 tileA[TILE_E];      // channels g*8+0..3
    __shared__ float4 tileB[TILE_E];      // channels g*8+4..7

    const int x   = threadIdx.x;          // 0..31
    const int hg  = threadIdx.y;          // 0..7
    const int tid = hg * TW + x;          // 0..255

    // XCD-aware bijective swizzle (r1-proven): each XCD gets a contiguous
    // wg range, spatial-fastest -> halo re-reads hit that XCD's L2.
    const int flat = blockIdx.x;                      // dispatch id, 0..959
    const int wg   = (flat & (NXCD - 1)) * WGPX + (flat >> 3);
    const int sp   = wg % NSP;                        // spatial tile (x-fastest)
    const int z    = wg / NSP;                        // 0..15
    const int wx   = sp % NSPX;
    const int wy   = sp / NSPX;

    const int w0 = wx * TW;
    const int h0 = wy * HTILE;
    const int b  = z & 3;
    const int c0 = (z >> 2) * CCHUNK;

    const int w = w0 + x;                 // always < WW
    const int h = h0 + hg;                // always < HH

    const float* tgt_b = tgt + (size_t)(b * CC + c0) * HWSZ;
    const float* src_p = src + (size_t)(b * CC + c0) * HWSZ + h * WW + w;

    // --- precompute staging slots (invariant across phases) ---
    int  sOff[3];
    bool sVal[3];
#pragma unroll
    for (int k = 0; k < 3; ++k) {
        const int idx = tid + k * 256;
        const int r   = idx / TCOLS;
        const int col = idx - r * TCOLS;
        const int gr  = h0 - RR + r;
        const int gc  = w0 - RR + col;
        sVal[k] = (idx < TILE_E) && gr >= 0 && gr < HH && gc >= 0 && gc < WW;
        sOff[k] = gr * WW + gc;
    }

    float4 prA[3], prB[3];                // tgt tile prefetch (6 f4/thread)
    float  sv8[8];                        // src prefetch (8 channels)

    auto fetch = [&](int g) {
        const float* t = tgt_b + (size_t)(g * CG) * HWSZ;
#pragma unroll
        for (int k = 0; k < 3; ++k) {
            float4 va = make_float4(0.f, 0.f, 0.f, 0.f);
            float4 vb = make_float4(0.f, 0.f, 0.f, 0.f);
            if (sVal[k]) {
                const float* p = t + sOff[k];
                va.x = p[0];
                va.y = p[HWSZ];
                va.z = p[2 * HWSZ];
                va.w = p[3 * HWSZ];
                vb.x = p[4 * HWSZ];
                vb.y = p[5 * HWSZ];
                vb.z = p[6 * HWSZ];
                vb.w = p[7 * HWSZ];
            }
            prA[k] = va;
            prB[k] = vb;
        }
        const float* s = src_p + (size_t)(g * CG) * HWSZ;
#pragma unroll
        for (int k = 0; k < 8; ++k) sv8[k] = s[k * HWSZ];
    };

    float acc[NS];
#pragma unroll
    for (int s = 0; s < NS; ++s) acc[s] = 0.f;

    fetch(0);
    const int base = (RR + hg) * TCOLS + (RR + x);

    for (int g = 0; g < NG; ++g) {
        // store-early: write staged regs to both LDS buffers (6x b128)
        tileA[tid]       = prA[0];
        tileA[tid + 256] = prA[1];
        if (tid + 512 < TILE_E) tileA[tid + 512] = prA[2];
        tileB[tid]       = prB[0];
        tileB[tid + 256] = prB[1];
        if (tid + 512 < TILE_E) tileB[tid + 512] = prB[2];
        // snapshot src scalars before fetch overwrites them
        const float a0 = sv8[0], a1 = sv8[1], a2 = sv8[2], a3 = sv8[3];
        const float b0 = sv8[4], b1 = sv8[5], b2 = sv8[6], b3 = sv8[7];
        __syncthreads();

        // depth-1 prefetch of next phase (flight window = ~680cyc compute)
        if (g + 1 < NG) fetch(g + 1);

        // compute: 34 ds_read_b128 + 136 FMAs (8 channels per phase)
        {
            float4 tc = tileA[base];
            FMA4S(acc[0], tc, a0, a1, a2, a3);
#pragma unroll
            for (int off = 1; off <= RR; ++off) {
                float4 tu = tileA[base - off * TCOLS];
                float4 td = tileA[base + off * TCOLS];
                float4 tl = tileA[base - off];
                float4 tr = tileA[base + off];
                FMA4S(acc[4 * off - 3], tu, a0, a1, a2, a3);
                FMA4S(acc[4 * off - 2], td, a0, a1, a2, a3);
                FMA4S(acc[4 * off - 1], tl, a0, a1, a2, a3);
                FMA4S(acc[4 * off    ], tr, a0, a1, a2, a3);
            }
            float4 uc = tileB[base];
            FMA4S(acc[0], uc, b0, b1, b2, b3);
#pragma unroll
            for (int off = 1; off <= RR; ++off) {
                float4 tu = tileB[base - off * TCOLS];
                float4 td = tileB[base + off * TCOLS];
                float4 tl = tileB[base - off];
                float4 tr = tileB[base + off];
                FMA4S(acc[4 * off - 3], tu, b0, b1, b2, b3);
                FMA4S(acc[4 * off - 2], td, b0, b1, b2, b3);
                FMA4S(acc[4 * off - 1], tl, b0, b1, b2, b3);
                FMA4S(acc[4 * off    ], tr, b0, b1, b2, b3);
            }
        }
        __syncthreads();
    }

    // epilogue: atomic accumulate (4 channel-chunk writers per output)
    float* op = out + (((size_t)b * NS) * HH + h) * WW + w;
#pragma unroll
    for (int s = 0; s < NS; ++s) {
        atomicAdd(op + (size_t)s * HWSZ, acc[s]);
    }
}

extern "C" void kernel_launch(void* const* d_in, const int* in_sizes, int n_in,
                              void* d_out, int out_size, void* d_ws, size_t ws_size,
                              hipStream_t stream) {
    const float* src = (const float*)d_in[0];
    const float* tgt = (const float*)d_in[1];
    float* out = (float*)d_out;

    // d_out is poisoned before every launch; we accumulate atomically -> zero it
    hipMemsetAsync(out, 0, (size_t)out_size * sizeof(float), stream);

    dim3 block(TW, 8, 1);      // 256 threads
    dim3 grid(NWG, 1, 1);      // 960 blocks
    cost_volume_kernel<<<grid, block, 0, stream>>>(src, tgt, out);
}

// Round 10
// 105.117 us; speedup vs baseline: 3.1598x; 1.0108x over previous
//
#include <hip/hip_runtime.h>

#define RR 4
#define NS 17
#define BB 4
#define CC 128
#define HH 96
#define WW 160
#define HWSZ (HH * WW)

// 512-thread block = two 256-thread channel-halves sharing one 32x8 pixel
// tile. Each half runs the r1-proven inner loop (store-early, 2 barriers/
// phase, depth-1 prefetch after first barrier) on its own 16 channels in its
// own LDS buffer; halves combine via LDS; half A does one 4-writer atomic pass.
//
// WHY 512 threads: grid occupancy. 960x256-thread blocks = 15 waves/CU (47%
// cap, 32% measured r8) and all blocks already resident -> the only wave
// lever that keeps writers/output at 4 is bigger blocks: 960x512 = 30/CU.
//
// SESSION LAWS (counter-proven):
//  - ATOMIC LAW: clean 4 B/atomic ONLY with <=4 writers/output on ONE XCD
//    (r0). 8 writers = 34 B/at even same-XCD (r5/r6); 4 writers spanning 4
//    XCDs = 15 B/at (r8). Mapping below: writers share xcd, 240 ids apart.
//  - VGPR LAW: never bound below the live set. r7's (512,8) forced VGPR=32
//    -> acc in scratch -> 400+MB symmetric fetch/write. THIS kernel uses
//    (512,4): cap 128, live set ~64. Tripwire: VGPR<=40 or sym-inflation.
//  - Store-early r1 skeleton only (write-late r2/r3 and depth-2 r8 dirty).
// TRIPWIRES: WRITE_SIZE ~16,320 KB; VGPR 56-80; FETCH 65-85 MB; occ >=60%.
#define TW 32
#define HTILE 8
#define TROWS (HTILE + 2 * RR)   // 16
#define TCOLS (TW + 2 * RR)      // 40
#define TILE_E (TROWS * TCOLS)   // 640 float4 = 10240 B per half-buffer
#define CCHUNK 32                // channels per BLOCK -> 4 writers/output
#define NCHUNK (CC / CCHUNK)     // 4 (atomic-accumulated)
#define CHALF (CCHUNK / 2)       // 16 channels per half
#define CG 4                     // channels per phase (float4)
#define NGH (CHALF / CG)         // 4 phases per half
#define NSPX (WW / TW)           // 5
#define NSPY (HH / HTILE)        // 12

#define FMA4(a, t) \
    (a) = fmaf(svx, (t).x, fmaf(svy, (t).y, fmaf(svz, (t).z, fmaf(svw, (t).w, (a)))))

__global__ __launch_bounds__(512, 4)
void cost_volume_kernel(const float* __restrict__ src,
                        const float* __restrict__ tgt,
                        float* __restrict__ out) {
    __shared__ float4 tile[2][TILE_E];    // one buffer per half: 20480 B

    const int x    = threadIdx.x;         // 0..31
    const int yy   = threadIdx.y;         // 0..15
    const int half = yy >> 3;             // 0/1 channel half (wave-uniform)
    const int hg   = yy & 7;              // 0..7 pixel row group
    const int tid  = hg * TW + x;         // 0..255 within half

    // XCD mapping (HW: xcd = flat dispatch id % 8):
    //   xcd -> (batch, image-half); i = flat>>3 -> 30 contiguous spatial
    //   tiles (fastest) x 4 chunks (slowest).
    //   => all 4 chunk-writers of an output: same xcd, 240 ids apart
    //      (r0's counter-proven clean-atomic configuration), and each
    //      XCD's fetch stream is spatially contiguous within one batch.
    const int flat = blockIdx.x;          // 0..959
    const int xcd  = flat & 7;
    const int i    = flat >> 3;           // 0..119
    const int b    = xcd & 3;
    const int sph  = xcd >> 2;            // 0..1: top/bottom image half
    const int spl  = i % 30;              // local spatial tile, fastest
    const int ch32 = i / 30;              // chunk 0..3, slowest
    const int wx   = spl % NSPX;
    const int wy   = sph * 6 + spl / NSPX;

    const int c0 = ch32 * CCHUNK + half * CHALF;
    const int w0 = wx * TW;
    const int h0 = wy * HTILE;

    const int w = w0 + x;                 // always < WW
    const int h = h0 + hg;                // always < HH

    const float* tgt_b = tgt + (size_t)(b * CC + c0) * HWSZ;
    const float* src_p = src + (size_t)(b * CC + c0) * HWSZ + h * WW + w;

    // --- precompute staging slots (invariant across phases) ---
    int  sOff[3];
    bool sVal[3];
#pragma unroll
    for (int k = 0; k < 3; ++k) {
        const int idx = tid + k * 256;
        const int r   = idx / TCOLS;
        const int col = idx - r * TCOLS;
        const int gr  = h0 - RR + r;
        const int gc  = w0 - RR + col;
        sVal[k] = (idx < TILE_E) && gr >= 0 && gr < HH && gc >= 0 && gc < WW;
        sOff[k] = gr * WW + gc;
    }

    float4 pre[3];                        // tgt tile prefetch (3 f4/thread)
    float  sv4[4];                        // src prefetch (4 channels)

    auto fetch = [&](int g) {
        const float* t = tgt_b + (size_t)(g * CG) * HWSZ;
#pragma unroll
        for (int k = 0; k < 3; ++k) {
            float4 v = make_float4(0.f, 0.f, 0.f, 0.f);
            if (sVal[k]) {
                const float* p = t + sOff[k];
                v.x = p[0];
                v.y = p[HWSZ];
                v.z = p[2 * HWSZ];
                v.w = p[3 * HWSZ];
            }
            pre[k] = v;
        }
        const float* s = src_p + (size_t)(g * CG) * HWSZ;
#pragma unroll
        for (int k = 0; k < 4; ++k) sv4[k] = s[k * HWSZ];
    };

    float acc[NS];
#pragma unroll
    for (int s = 0; s < NS; ++s) acc[s] = 0.f;

    fetch(0);
    const int base = (RR + hg) * TCOLS + (RR + x);
    float4* tb = tile[half];

    for (int g = 0; g < NGH; ++g) {
        // store-early: write staged regs to this half's LDS buffer
        tb[tid]       = pre[0];
        tb[tid + 256] = pre[1];
        if (tid + 512 < TILE_E) tb[tid + 512] = pre[2];
        const float svx = sv4[0], svy = sv4[1], svz = sv4[2], svw = sv4[3];
        __syncthreads();

        // depth-1 prefetch of next phase while computing this one
        if (g + 1 < NGH) fetch(g + 1);

        // compute: 17 ds_read_b128 + 68 FMAs (4 channels at once)
        {
            float4 tc = tb[base];
            FMA4(acc[0], tc);
#pragma unroll
            for (int off = 1; off <= RR; ++off) {
                float4 tu = tb[base - off * TCOLS];
                float4 td = tb[base + off * TCOLS];
                float4 tl = tb[base - off];
                float4 tr = tb[base + off];
                FMA4(acc[4 * off - 3], tu);
                FMA4(acc[4 * off - 2], td);
                FMA4(acc[4 * off - 1], tl);
                FMA4(acc[4 * off    ], tr);
            }
        }
        __syncthreads();
    }

    // --- combine halves in LDS, then 4-writer atomic epilogue ---
    // (last loop barrier ordered all tile reads before this reuse)
    // stride NS=17 odd -> bijective mod 32 banks, conflict-free;
    // 4352 floats fit in the 5120-float tile allocation.
    float* red = (float*)tile;
    if (half) {
#pragma unroll
        for (int s = 0; s < NS; ++s) red[tid * NS + s] = acc[s];
    }
    __syncthreads();
    if (!half) {
        float* op = out + (((size_t)b * NS) * HH + h) * WW + w;
#pragma unroll
        for (int s = 0; s < NS; ++s) {
            atomicAdd(op + (size_t)s * HWSZ, acc[s] + red[tid * NS + s]);
        }
    }
}

extern "C" void kernel_launch(void* const* d_in, const int* in_sizes, int n_in,
                              void* d_out, int out_size, void* d_ws, size_t ws_size,
                              hipStream_t stream) {
    const float* src = (const float*)d_in[0];
    const float* tgt = (const float*)d_in[1];
    float* out = (float*)d_out;

    // d_out is poisoned before every launch; we accumulate atomically -> zero it
    hipMemsetAsync(out, 0, (size_t)out_size * sizeof(float), stream);

    dim3 block(TW, 16, 1);                // 512 threads = two 256-halves
    dim3 grid(NSPX * NSPY * BB * NCHUNK, 1, 1);  // 960 blocks, 1D for mapping
    cost_volume_kernel<<<grid, block, 0, stream>>>(src, tgt, out);
}